// Round 1
// baseline (5898.890 us; speedup 1.0000x reference)
//
#include <hip/hip_runtime.h>
#include <hip/hip_bf16.h>

// Sizes (fixed by the problem)
#define BB   128
#define TM1  64
#define MM   512
#define PP   512

__device__ __forceinline__ float fast_tanh(float x) {
    // tanh(x) = 1 - 2/(e^{2x}+1); robust for +-inf
    float e = __expf(2.0f * x);
    return 1.0f - 2.0f / (e + 1.0f);
}
__device__ __forceinline__ float fast_sigmoid(float x) {
    return 1.0f / (1.0f + __expf(-x));
}

// -------------------------------------------------------------------------
// Kernel A: hx[n,e] = sum_m X[n,m] * Wa1[e,1024+m] + ba1[e]
//   n in [0,8192) (b*64+t), e in [0,512)
// 64x64 tile, 256 threads, 4x4 microtile, BK=16
// -------------------------------------------------------------------------
__global__ __launch_bounds__(256) void k_hx(
    const float* __restrict__ X, const float* __restrict__ Wa1,
    const float* __restrict__ ba1, float* __restrict__ hx)
{
    __shared__ float As[64][17];
    __shared__ float Bs[64][17];
    const int n0 = blockIdx.x * 64;   // 128 tiles
    const int e0 = blockIdx.y * 64;   // 8 tiles
    const int tid = threadIdx.x;
    const int tr = tid >> 4, tc = tid & 15;
    float acc[4][4] = {};
    for (int k0 = 0; k0 < 512; k0 += 16) {
#pragma unroll
        for (int i = 0; i < 4; ++i) {
            int idx = tid + i * 256;          // 0..1023
            int r = idx >> 4, kk = idx & 15;
            As[r][kk] = X[(size_t)(n0 + r) * 512 + k0 + kk];
            Bs[r][kk] = Wa1[(size_t)(e0 + r) * 1536 + 1024 + k0 + kk];
        }
        __syncthreads();
#pragma unroll
        for (int kk = 0; kk < 16; ++kk) {
            float a[4], b[4];
#pragma unroll
            for (int i = 0; i < 4; ++i) a[i] = As[tr * 4 + i][kk];
#pragma unroll
            for (int j = 0; j < 4; ++j) b[j] = Bs[tc * 4 + j][kk];
#pragma unroll
            for (int i = 0; i < 4; ++i)
#pragma unroll
                for (int j = 0; j < 4; ++j) acc[i][j] += a[i] * b[j];
        }
        __syncthreads();
    }
#pragma unroll
    for (int i = 0; i < 4; ++i) {
        int n = n0 + tr * 4 + i;
#pragma unroll
        for (int j = 0; j < 4; ++j) {
            int e = e0 + tc * 4 + j;
            hx[(size_t)n * 512 + e] = acc[i][j] + ba1[e];
        }
    }
}

// -------------------------------------------------------------------------
// Kernel B (phase 1, per step):
//   cols [0,512):    s[b,col]   = sum_{k<512} d[b,k]*Wa1[col,k] + c[b,k]*Wa1[col,512+k]
//   cols [512,2560): glin[b,j]  = sum_k d[b,k]*Whh[j,k] + bih[j] + bhh[j],  j=col-512
// 32x32 tiles, 256 threads, 2x2 microtile, BK=32. grid = (80 col-tiles, 4 row-tiles)
// -------------------------------------------------------------------------
__global__ __launch_bounds__(256) void k_phase1(
    const float* __restrict__ d_st, const float* __restrict__ c_st,
    const float* __restrict__ Wa1, const float* __restrict__ Whh,
    const float* __restrict__ bih, const float* __restrict__ bhh,
    float* __restrict__ s_out, float* __restrict__ glin)
{
    __shared__ float As[32][33];
    __shared__ float Bs[32][33];
    const int c0 = blockIdx.x * 32;
    const int b0 = blockIdx.y * 32;
    const bool is_s = (c0 < 512);
    const int K = is_s ? 1024 : 512;
    const int tid = threadIdx.x;
    const int tr = tid >> 4, tc = tid & 15;
    float acc[2][2] = {};
    for (int k0 = 0; k0 < K; k0 += 32) {
#pragma unroll
        for (int i = 0; i < 4; ++i) {
            int idx = tid + i * 256;          // 0..1023
            int r = idx >> 5, kk = idx & 31;
            int k = k0 + kk;
            float v;
            if (is_s) v = (k < 512) ? d_st[(b0 + r) * 512 + k]
                                    : c_st[(b0 + r) * 512 + (k - 512)];
            else      v = d_st[(b0 + r) * 512 + k];
            As[r][kk] = v;
        }
#pragma unroll
        for (int i = 0; i < 4; ++i) {
            int idx = tid + i * 256;
            int r = idx >> 5, kk = idx & 31;
            int k = k0 + kk;
            int col = c0 + r;
            Bs[r][kk] = is_s ? Wa1[(size_t)col * 1536 + k]
                             : Whh[(size_t)(col - 512) * 512 + k];
        }
        __syncthreads();
#pragma unroll
        for (int kk = 0; kk < 32; ++kk) {
            float a0 = As[tr * 2][kk], a1 = As[tr * 2 + 1][kk];
            float w0 = Bs[tc * 2][kk], w1 = Bs[tc * 2 + 1][kk];
            acc[0][0] += a0 * w0; acc[0][1] += a0 * w1;
            acc[1][0] += a1 * w0; acc[1][1] += a1 * w1;
        }
        __syncthreads();
    }
#pragma unroll
    for (int i = 0; i < 2; ++i) {
        int b = b0 + tr * 2 + i;
#pragma unroll
        for (int j = 0; j < 2; ++j) {
            int col = c0 + tc * 2 + j;
            if (is_s) {
                s_out[b * 512 + col] = acc[i][j];
            } else {
                int jj = col - 512;
                glin[b * 2048 + jj] = acc[i][j] + bih[jj] + bhh[jj];
            }
        }
    }
}

// -------------------------------------------------------------------------
// Kernel C (phase 2, per step): one block per batch-PAIR (softmax couples
// batches 2p and 2p+1 due to the reference's raw reshape).
//   scores -> joint-128 softmax -> context -> y_tilde -> gates -> LSTM update
// 64 blocks x 512 threads.
// -------------------------------------------------------------------------
__global__ __launch_bounds__(512) void k_phase2(
    const float* __restrict__ Xe, const float* __restrict__ yprev,
    const float* __restrict__ Wa2, const float* __restrict__ ba2,
    const float* __restrict__ Wih, const float* __restrict__ Wfc,
    const float* __restrict__ bfc, const float* __restrict__ s_in,
    const float* __restrict__ glin, float* __restrict__ d_st,
    float* __restrict__ c_st, float* __restrict__ ctx_out,
    const float* __restrict__ hx, int t)
{
    __shared__ float sh_s[2][512];
    __shared__ float sh_w[512];
    __shared__ float sc[128];
    __shared__ float ctxl[2][512];
    __shared__ float ytl[2];
    __shared__ float red0;

    const int p = blockIdx.x;
    const int b0 = p * 2;
    const int tid = threadIdx.x;

    sh_s[0][tid >> 9 ? 0 : tid] = s_in[b0 * 512 + tid];          // tid<512 always
    sh_s[1][tid] = s_in[(b0 + 1) * 512 + tid];
    sh_w[tid] = Wa2[tid];
    __syncthreads();

    // ---- scores: 8 waves x 16 (b,t) units, each a 512-dot with tanh ----
    const int wave = tid >> 6, lane = tid & 63;
    for (int u0 = 0; u0 < 16; ++u0) {
        int u = wave * 16 + u0;
        int bl = u >> 6, tt = u & 63;
        const float* hr = hx + ((size_t)(b0 + bl) * 64 + tt) * 512;
        const float* ss = sh_s[bl];
        float acc = 0.f;
#pragma unroll
        for (int j = 0; j < 8; ++j) {
            int e = lane + j * 64;
            acc += sh_w[e] * fast_tanh(ss[e] + hr[e]);
        }
#pragma unroll
        for (int off = 32; off; off >>= 1) acc += __shfl_xor(acc, off, 64);
        if (lane == 0) sc[u] = acc + ba2[0];
    }
    __syncthreads();

    // ---- joint softmax over the 128 scores of the pair ----
    if (tid < 64) {
        float m2 = fmaxf(sc[tid], sc[tid + 64]);
#pragma unroll
        for (int off = 32; off; off >>= 1) m2 = fmaxf(m2, __shfl_xor(m2, off, 64));
        float e0v = __expf(sc[tid] - m2);
        float e1v = __expf(sc[tid + 64] - m2);
        sc[tid] = e0v; sc[tid + 64] = e1v;
        float ssum = e0v + e1v;
#pragma unroll
        for (int off = 32; off; off >>= 1) ssum += __shfl_xor(ssum, off, 64);
        if (tid == 0) red0 = 1.0f / ssum;
    }
    __syncthreads();
    const float inv = red0;

    // ---- context[b,m] = inv * sum_t sc[b,t] * Xe[b,t,m] ----
#pragma unroll
    for (int rep = 0; rep < 2; ++rep) {
        int idx = tid + rep * 512;
        int bl = idx >> 9, m = idx & 511;
        const float* xr = Xe + (size_t)(b0 + bl) * 64 * 512 + m;
        const float* bbv = sc + bl * 64;
        float acc = 0.f;
#pragma unroll 8
        for (int tt = 0; tt < 64; ++tt) acc += bbv[tt] * xr[(size_t)tt * 512];
        ctxl[bl][m] = acc * inv;
    }
    __syncthreads();

    // ---- y_tilde[b] = ctx . Wfc[0:512] + Wfc[512]*y_prev[b,t] + bfc ----
    if (tid < 128) {
        int bl = tid >> 6, l2 = tid & 63;
        float acc = 0.f;
#pragma unroll
        for (int j = 0; j < 8; ++j) {
            int m = l2 + j * 64;
            acc += ctxl[bl][m] * Wfc[m];
        }
#pragma unroll
        for (int off = 32; off; off >>= 1) acc += __shfl_xor(acc, off, 64);
        if (l2 == 0)
            ytl[bl] = acc + Wfc[512] * yprev[(b0 + bl) * 64 + t] + bfc[0];
    }
    __syncthreads();

    // ---- gates + LSTM update (i,f,g,o gate order) ----
#pragma unroll
    for (int rep = 0; rep < 2; ++rep) {
        int idx = tid + rep * 512;
        int bl = idx >> 9, pp = idx & 511;
        int b = b0 + bl;
        float yt = ytl[bl];
        const float* gl = glin + (size_t)b * 2048;
        float ii = gl[pp]        + yt * Wih[pp];
        float ff = gl[512 + pp]  + yt * Wih[512 + pp];
        float gg = gl[1024 + pp] + yt * Wih[1024 + pp];
        float oo = gl[1536 + pp] + yt * Wih[1536 + pp];
        float cprev = c_st[(size_t)b * 512 + pp];
        float cn = fast_sigmoid(ff) * cprev + fast_sigmoid(ii) * fast_tanh(gg);
        float dn = fast_sigmoid(oo) * fast_tanh(cn);
        c_st[(size_t)b * 512 + pp] = cn;
        d_st[(size_t)b * 512 + pp] = dn;
        if (t == 63) ctx_out[(size_t)b * 512 + pp] = ctxl[bl][pp];
    }
}

// -------------------------------------------------------------------------
// Kernel D: out[b] = [d | ctx] . Wfin + bfin
// -------------------------------------------------------------------------
__global__ __launch_bounds__(128) void k_final(
    const float* __restrict__ d_st, const float* __restrict__ ctx,
    const float* __restrict__ Wfin, const float* __restrict__ bfin,
    float* __restrict__ out)
{
    int b = threadIdx.x;
    float acc = bfin[0];
    for (int k = 0; k < 512; ++k) acc += d_st[b * 512 + k] * Wfin[k];
    for (int k = 0; k < 512; ++k) acc += ctx[b * 512 + k] * Wfin[512 + k];
    out[b] = acc;
}

extern "C" void kernel_launch(void* const* d_in, const int* in_sizes, int n_in,
                              void* d_out, int out_size, void* d_ws, size_t ws_size,
                              hipStream_t stream)
{
    const float* Xe   = (const float*)d_in[0];
    const float* ypr  = (const float*)d_in[1];
    const float* Wa1  = (const float*)d_in[2];
    const float* ba1  = (const float*)d_in[3];
    const float* Wa2  = (const float*)d_in[4];
    const float* ba2  = (const float*)d_in[5];
    const float* Wih  = (const float*)d_in[6];
    const float* Whh  = (const float*)d_in[7];
    const float* bih  = (const float*)d_in[8];
    const float* bhh  = (const float*)d_in[9];
    const float* Wfc  = (const float*)d_in[10];
    const float* bfc  = (const float*)d_in[11];
    const float* Wfin = (const float*)d_in[12];
    const float* bfin = (const float*)d_in[13];
    float* out = (float*)d_out;

    float* ws   = (float*)d_ws;
    float* hx   = ws;                          // 8192*512      = 4,194,304
    float* s    = hx + (size_t)8192 * 512;     // 128*512
    float* glin = s + 128 * 512;               // 128*2048
    float* dst  = glin + 128 * 2048;           // 128*512
    float* cst  = dst + 128 * 512;             // 128*512
    float* ctx  = cst + 128 * 512;             // 128*512
    // total ~18.9 MB of f32 workspace

    // zero initial d and c (contiguous)
    hipMemsetAsync(dst, 0, (size_t)2 * 128 * 512 * sizeof(float), stream);

    dim3 gA(128, 8);
    k_hx<<<gA, 256, 0, stream>>>(Xe, Wa1, ba1, hx);

    for (int t = 0; t < 64; ++t) {
        dim3 gB(80, 4);
        k_phase1<<<gB, 256, 0, stream>>>(dst, cst, Wa1, Whh, bih, bhh, s, glin);
        k_phase2<<<64, 512, 0, stream>>>(Xe, ypr, Wa2, ba2, Wih, Wfc, bfc,
                                         s, glin, dst, cst, ctx, hx, t);
    }

    k_final<<<1, 128, 0, stream>>>(dst, ctx, Wfin, bfin, out);
}